// Round 8
// baseline (260.693 us; speedup 1.0000x reference)
//
#include <hip/hip_runtime.h>
#include <hip/hip_bf16.h>

using bf16 = __hip_bfloat16;
typedef __bf16 bf16x4v __attribute__((ext_vector_type(4)));
typedef __bf16 bf16x8 __attribute__((ext_vector_type(8)));
typedef float f32x4 __attribute__((ext_vector_type(4)));

#define MT 32            // tokens per block
#define SX 136           // xs row stride: 128 + 8 pad
#define SH 264           // hs row stride: 256 + 8
#define SJ 20            // NTF j-stride: 17 joints + 3 zero pad (40 B rows)
#define TFS 640          // NTF token stride = 32 * SJ
#define NTF_ELEMS 20480  // 32 tokens * 32 feats * SJ
#define MS_BASE 20496    // NTF + 16-elem zeroed tail
#define SMS 36           // Ms row stride (72 B; 18*l mod 32 distinct -> conflict-light)
#define MSW 612          // per-wave Ms: [17][36] written; reads overrun into next wave (safe)
#define S_ELEMS 25936    // 20496 + 7*612 + 1152 read-tail = 51872 B -> 3 blocks/CU by LDS
// 512 threads (8 waves). EXPERIMENT (single variable vs round 7): launch_bounds
// (512,4) -> (512,6). Rationale: 3 blocks/CU needs 6 waves/SIMD, i.e. total
// (VGPR+AGPR, unified file, ~512/SIMD pool) <= ~85 regs/wave. Round 7 at (512,4)
// compiled to 52 arch VGPR (+AGPRs) and HW ran only 2 blocks (occupancy 40.5% ==
// round 5's 2-block signature) despite LDS fitting 3. Round 6 at (512,6) DID get
// 3 blocks resident (58%) but regressed on ~80 MB spill traffic -- confounded with
// the since-deleted array-based coord epilogue. This round isolates the bound with
// the lean round-7 body. Gate: WRITE_SIZE must stay ~8.7 MB (no spills).
// LDS plan:
//   xs [32][136] @ 0, hs [32][264] @ 4352    (GEMM1 phase; dead after hs reg-capture)
//   NTF[t][f][j] @ 0  (t*640 + f*20 + j)     node state, overlays xs+hs
//   Ms  @ 20496 + w*612: per-WAVE [17][36]   i-major scratch for ONE token (row = i)
// After the GEMM2 barrier, ALL accesses are wave-local: no __syncthreads in GAT/coord.
// Wg m-tile 1 reads Ms rows 16..31: rows 17..31 are the next wave's live data or the
// tail -- garbage is safe: MFMA D-rows depend only on the same A-row (row-confined),
// and every D-row with i>16 is store-masked.

__device__ __forceinline__ float bf2f(bf16 v) { return __bfloat162float(v); }

__device__ __forceinline__ float gelu_f(float x) {
    // tanh-approx GELU (|err| <= ~3e-3 abs); raw v_rcp (1e-5 rel) instead of div.
    float u  = x * fmaf(0.035677408f * x, x, 0.7978845608f);
    float au = fabsf(u);
    float e  = __expf(-2.0f * au);
    float t  = (1.0f - e) * __builtin_amdgcn_rcpf(1.0f + e);
    t = (u < 0.0f) ? -t : t;
    float hx = 0.5f * x;
    return fmaf(hx, t, hx);
}

__device__ __forceinline__ bf16x8 ld8(const bf16* p) {       // 16B-aligned
    return *reinterpret_cast<const bf16x8*>(p);
}
__device__ __forceinline__ bf16x8 ld8u(const bf16* p) {      // 8B-aligned (two b64)
    bf16x4v lo = *reinterpret_cast<const bf16x4v*>(p);
    bf16x4v hi = *reinterpret_cast<const bf16x4v*>(p + 4);
    return __builtin_shufflevector(lo, hi, 0, 1, 2, 3, 4, 5, 6, 7);
}
__device__ __forceinline__ f32x4 mfma16(bf16x8 a, bf16x8 b, f32x4 c) {
    return __builtin_amdgcn_mfma_f32_16x16x32_bf16(a, b, c, 0, 0, 0);
}

// ---------------- prep: weight transposes + adjacency softmax ----------------
__global__ void prep_kernel(const float* __restrict__ W1, const float* __restrict__ W2,
                            const float* __restrict__ Wg1, const float* __restrict__ Wg2,
                            const float* __restrict__ adj1, const float* __restrict__ adj2,
                            bf16* __restrict__ w1t, bf16* __restrict__ w2t,
                            bf16* __restrict__ wg1t, bf16* __restrict__ wg2t,
                            float* __restrict__ A1f, float* __restrict__ A2f) {
    int idx = blockIdx.x * 256 + threadIdx.x;
    if (idx < 32768) {                       // W1: r=k(128), c=n(256)
        int r = idx >> 8, c = idx & 255;
        w1t[c * 128 + r] = __float2bfloat16(W1[idx]);
    } else if (idx < 172032) {               // W2: r=k(256), c=n(544)
        int j = idx - 32768;
        int r = j / 544, c = j % 544;
        w2t[c * 256 + r] = __float2bfloat16(W2[j]);
    } else if (idx < 173056) {               // Wg1 -> wg1t[f'][f]
        int j = idx - 172032;
        wg1t[(j & 31) * 32 + (j >> 5)] = __float2bfloat16(Wg1[j]);
    } else if (idx < 174080) {
        int j = idx - 173056;
        wg2t[(j & 31) * 32 + (j >> 5)] = __float2bfloat16(Wg2[j]);
    }
    if (blockIdx.x == 0) {
        int t = threadIdx.x;
        if (t < 17 || (t >= 32 && t < 49)) {
            const float* adj = (t < 17) ? adj1 : adj2;
            float*       A   = (t < 17) ? A1f  : A2f;
            int row = (t < 17) ? t : (t - 32);
            float v[17]; float mx = -1e30f;
            for (int j = 0; j < 17; ++j) { v[j] = adj[row * 17 + j]; mx = fmaxf(mx, v[j]); }
            float s = 0.0f;
            for (int j = 0; j < 17; ++j) { v[j] = __expf(v[j] - mx); s += v[j]; }
            float inv = 1.0f / s;
            for (int j = 0; j < 17; ++j) A[row * 17 + j] = v[j] * inv;
        }
    }
}

// ---------------- main fused kernel ----------------
__global__ __launch_bounds__(512, 6)
void gat_main(const float* __restrict__ x,
              const float* __restrict__ b1, const float* __restrict__ b2,
              const float* __restrict__ bg1, const float* __restrict__ bg2,
              const bf16* __restrict__ w1t, const bf16* __restrict__ w2t,
              const bf16* __restrict__ wg1t, const bf16* __restrict__ wg2t,
              const float* __restrict__ A1, const float* __restrict__ A2,
              const float* __restrict__ Wc, const float* __restrict__ bc,
              float* __restrict__ out) {
    __shared__ alignas(16) bf16 S[S_ELEMS];
    bf16* xs = S;            // [32][SX]
    bf16* hs = S + 4352;     // [32][SH]

    const int tid  = threadIdx.x;
    const int w    = tid >> 6;      // 0..7
    const int lane = tid & 63;
    const int l    = lane & 15;
    const int q    = lane >> 4;
    const int t0   = blockIdx.x * MT;

    // ---- stage x tile (fp32 -> bf16) ----
    for (int c = tid; c < 1024; c += 512) {
        int row = c >> 5, c4 = c & 31;
        const float4 v = *reinterpret_cast<const float4*>(x + (size_t)(t0 + row) * 128 + c4 * 4);
        bf16 tmp[4] = { __float2bfloat16(v.x), __float2bfloat16(v.y),
                        __float2bfloat16(v.z), __float2bfloat16(v.w) };
        *reinterpret_cast<ushort4*>(xs + row * SX + c4 * 4) =
            *reinterpret_cast<const ushort4*>(tmp);
    }
    __syncthreads();

    // ---- GEMM1: h = gelu(x @ W1 + b1)  [32,128]@[128,256], 2 n-tiles/wave ----
    for (int nt = w * 2; nt < w * 2 + 2; ++nt) {
        int n = nt * 16 + l;
        bf16x8 bfr[4];
        const bf16* wp = w1t + n * 128 + q * 8;
#pragma unroll
        for (int kf = 0; kf < 4; ++kf) bfr[kf] = ld8(wp + kf * 32);
        float bias = b1[n];
#pragma unroll
        for (int mt = 0; mt < 2; ++mt) {
            f32x4 acc = {0.f, 0.f, 0.f, 0.f};
            const bf16* ap = xs + (mt * 16 + l) * SX + q * 8;
#pragma unroll
            for (int kf = 0; kf < 4; ++kf)
                acc = mfma16(ld8(ap + kf * 32), bfr[kf], acc);
            int trow = mt * 16 + q * 4;
#pragma unroll
            for (int r = 0; r < 4; ++r)
                hs[(trow + r) * SH + n] = __float2bfloat16(gelu_f(acc[r] + bias));
        }
    }
    __syncthreads();

    // ---- GEMM2: nodes = h @ W2 + b2 -> NTF[t][f][i] scatter (overlays xs+hs) ----
    {
        bf16x8 af[2][8];    // register-capture all of this thread's hs fragments
#pragma unroll
        for (int mt = 0; mt < 2; ++mt)
#pragma unroll
            for (int kf = 0; kf < 8; ++kf)
                af[mt][kf] = ld8(hs + (mt * 16 + l) * SH + kf * 32 + q * 8);
        __syncthreads();     // hs fully captured before NTF (overlaying) is written

        // zero NTF pad: j=17..19 of every (t,f) row + 16-elem tail (mix over-reads
        // hit these; must be non-NaN; mixB zeros annihilate their contribution)
        for (int z = tid; z < 3072; z += 512) {
            int row = z / 3, k = z - row * 3;
            S[row * SJ + 17 + k] = __float2bfloat16(0.f);
        }
        if (tid < 16) S[NTF_ELEMS + tid] = __float2bfloat16(0.f);

        for (int nt = w; nt < 34; nt += 8) {
            int n = nt * 16 + l;
            float bias = b2[n];
            int i = n >> 5, f = n & 31;
            f32x4 a0 = {0.f, 0.f, 0.f, 0.f}, a1 = {0.f, 0.f, 0.f, 0.f};
            const bf16* wp = w2t + n * 256 + q * 8;
#pragma unroll
            for (int kf = 0; kf < 8; ++kf) {
                bf16x8 bfr = ld8(wp + kf * 32);
                a0 = mfma16(af[0][kf], bfr, a0);
                a1 = mfma16(af[1][kf], bfr, a1);
            }
#pragma unroll
            for (int mt = 0; mt < 2; ++mt) {
                const f32x4 acc = mt ? a1 : a0;
#pragma unroll
                for (int r = 0; r < 4; ++r) {
                    int t = mt * 16 + q * 4 + r;
                    S[t * TFS + f * SJ + i] = __float2bfloat16(acc[r] + bias);
                }
            }
        }
    }
    __syncthreads();
    // ======== from here on, everything is WAVE-LOCAL: no more barriers ========

    bf16* ms_w = S + MS_BASE + w * MSW;    // this wave's [17][36] i-major scratch

    for (int g = 0; g < 2; ++g) {
        const float* A  = g ? A2 : A1;
        const bf16* wgt = g ? wg2t : wg1t;
        const float* bg = g ? bg2 : bg1;

        // mix B-frags: B[k=j][col=i] = A_soft[i][j]; exact zeros for i>=17 or j>=17
        bf16x8 mixB[2];
#pragma unroll
        for (int nt = 0; nt < 2; ++nt) {
            int i = nt * 16 + l;
            bf16 tmp[8];
#pragma unroll
            for (int e = 0; e < 8; ++e) {
                int j = q * 8 + e;
                float v = (i < 17 && j < 17) ? A[i * 17 + j] : 0.0f;
                tmp[e] = __float2bfloat16(v);
            }
            mixB[nt] = *reinterpret_cast<bf16x8*>(tmp);
        }
        bf16x8 wfr[2];
#pragma unroll
        for (int nt = 0; nt < 2; ++nt) wfr[nt] = ld8(wgt + (nt * 16 + l) * 32 + q * 8);
        float bgf[2] = { bg[l], bg[16 + l] };

        // four 1-token chunks per wave (wave owns tokens w*4 .. w*4+3)
        for (int c = 0; c < 4; ++c) {
            const int T = w * 4 + c;

            // ---- mix GEMM: mixT[(f)][i] -> ms_w[i][f]  (i-major, one token) ----
#pragma unroll
            for (int mt2 = 0; mt2 < 2; ++mt2) {
                int R = T * 32 + mt2 * 16 + l;             // NTF row (t*32+f)
                bf16x8 afr = ld8u(S + R * SJ + q * 8);     // pad/overread killed by mixB zeros
                int f0 = mt2 * 16 + q * 4;                 // 4 consecutive f (D-rows)
#pragma unroll
                for (int nt = 0; nt < 2; ++nt) {
                    f32x4 acc = {0.f, 0.f, 0.f, 0.f};
                    acc = mfma16(afr, mixB[nt], acc);
                    int i = nt * 16 + l;
                    if (i < 17) {
                        union { ushort4 u; bf16 b[4]; } pk;
#pragma unroll
                        for (int r = 0; r < 4; ++r) pk.b[r] = __float2bfloat16(acc[r]);
                        *reinterpret_cast<ushort4*>(ms_w + i * SMS + f0) = pk.u;
                    }
                }
            }

            // ---- Wg GEMM + gelu + residual, VECTOR b64 RMW into NTF ----
            // D-rows are i directly; thread's 4 accs = 4 consecutive i for one f'.
#pragma unroll
            for (int mt = 0; mt < 2; ++mt) {
                bf16x8 afr = ld8u(ms_w + (mt * 16 + l) * SMS + q * 8);
                int i0 = mt * 16 + q * 4;                  // 0,4,8,12 | 16,20,24,28
#pragma unroll
                for (int nt = 0; nt < 2; ++nt) {
                    f32x4 acc = {0.f, 0.f, 0.f, 0.f};
                    acc = mfma16(afr, wfr[nt], acc);
                    int fp = nt * 16 + l;
                    if (i0 < 17) {
                        bf16* p = S + T * TFS + fp * SJ + i0;
                        union { ushort4 u; bf16 b[4]; } old, nw;
                        old.u = *reinterpret_cast<const ushort4*>(p);
#pragma unroll
                        for (int r = 0; r < 4; ++r) {
                            float v = gelu_f(acc[r] + bgf[nt]) + bf2f(old.b[r]);
                            if (i0 + r > 16) v = 0.0f;     // i0==16 quad: keep pads zero
                            nw.b[r] = __float2bfloat16(v);
                        }
                        *reinterpret_cast<ushort4*>(p) = nw.u;
                    }
                }
            }
        }
    }

    // ---- coord projection (wave-local, round-5 proven form): out = g2 @ Wc + bc ----
    for (int s = lane; s < 68; s += 64) {
        int tl = s / 17, i = s - tl * 17;
        int t  = w * 4 + tl;
        const bf16* gp = S + t * TFS + i;
        float o0 = bc[0], o1 = bc[1];
#pragma unroll
        for (int f = 0; f < 32; ++f) {
            float v = bf2f(gp[f * SJ]);
            o0 = fmaf(v, Wc[f * 2 + 0], o0);
            o1 = fmaf(v, Wc[f * 2 + 1], o1);
        }
        float2 pr = { o0, o1 };
        reinterpret_cast<float2*>(out)[(size_t)(t0 + t) * 17 + i] = pr;
    }
}

extern "C" void kernel_launch(void* const* d_in, const int* in_sizes, int n_in,
                              void* d_out, int out_size, void* d_ws, size_t ws_size,
                              hipStream_t stream) {
    const float* x    = (const float*)d_in[0];
    const float* W1   = (const float*)d_in[1];
    const float* b1   = (const float*)d_in[2];
    const float* W2   = (const float*)d_in[3];
    const float* b2   = (const float*)d_in[4];
    const float* adj1 = (const float*)d_in[5];
    const float* Wg1  = (const float*)d_in[6];
    const float* bg1  = (const float*)d_in[7];
    const float* adj2 = (const float*)d_in[8];
    const float* Wg2  = (const float*)d_in[9];
    const float* bg2  = (const float*)d_in[10];
    const float* Wc   = (const float*)d_in[11];
    const float* bc   = (const float*)d_in[12];

    char* ws = (char*)d_ws;
    bf16*  w1t  = (bf16*)(ws + 0);        // 65536 B
    bf16*  w2t  = (bf16*)(ws + 65536);    // 278528 B
    bf16*  wg1t = (bf16*)(ws + 344064);   // 2048 B
    bf16*  wg2t = (bf16*)(ws + 346112);   // 2048 B
    float* A1f  = (float*)(ws + 348160);  // 1156 B
    float* A2f  = (float*)(ws + 349376);  // 1156 B

    prep_kernel<<<680, 256, 0, stream>>>(W1, W2, Wg1, Wg2, adj1, adj2,
                                         w1t, w2t, wg1t, wg2t, A1f, A2f);

    const int tokens = 16 * 4096;
    gat_main<<<tokens / MT, 512, 0, stream>>>(x, b1, b2, bg1, bg2,
                                              w1t, w2t, wg1t, wg2t,
                                              A1f, A2f, Wc, bc, (float*)d_out);
}

// Round 9
// 218.075 us; speedup vs baseline: 1.1954x; 1.1954x over previous
//
#include <hip/hip_runtime.h>
#include <hip/hip_bf16.h>

using bf16 = __hip_bfloat16;
typedef __bf16 bf16x4v __attribute__((ext_vector_type(4)));
typedef __bf16 bf16x8 __attribute__((ext_vector_type(8)));
typedef float f32x4 __attribute__((ext_vector_type(4)));

#define MT 32            // tokens per block
#define SX 136           // xs row stride: 128 + 8 pad
#define SH 264           // hs row stride: 256 + 8
#define SJ 20            // NTF j-stride: 17 joints + 3 zero pad (40 B rows)
#define TFS 640          // NTF token stride = 32 * SJ
#define NTF_ELEMS 20480  // 32 tokens * 32 feats * SJ
#define MS_BASE 20496    // NTF + 16-elem zeroed tail
#define SMS 36           // Ms row stride (72 B; 18*l mod 32 distinct -> conflict-light)
#define MSW 1224         // per-wave pair-Ms: [34][36] (rows 0..31 = two tokens' i 0..15;
                         //  rows 32,33 = the two i=16 rows)
#define S_ELEMS 30800    // 20496 + 8*1224 + 512 read-tail = 61600 B
// 512 threads (8 waves), launch_bounds (512,4) -- PERMANENT after rounds 6+8 both showed
// (512,6)'s register budget forces ~80 MB/launch of spill traffic with ANY body (net
// regression). 2 blocks/CU (4 waves/SIMD) is this structure's ceiling; the unified
// VGPR+AGPR file (~104/wave at 52 arch VGPR) is the limiter, not LDS. This round cuts
// issued VALU instead (pair-Ms 3-tile Wg, 9-op gelu, precomputed mixB tables).
// LDS plan:
//   xs [32][136] @ 0, hs [32][264] @ 4352    (GEMM1 phase; dead after hs reg-capture)
//   NTF[t][f][j] @ 0  (t*640 + f*20 + j)     node state, overlays xs+hs
//   pair-Ms @ 20496 + w*1224: per-WAVE [34][36], i-major for a 2-token pair
// After the GEMM2 barrier, ALL accesses are wave-local: no __syncthreads in GAT/coord.
// Wg m-tile 2 reads Ms rows 32..47: rows 34..47 land in the next wave's live region or
// the 512-elem tail -- garbage-safe: MFMA D-rows depend only on the same A-row
// (row-confined), and D-rows 34..47 are never stored.

__device__ __forceinline__ float bf2f(bf16 v) { return __bfloat162float(v); }

__device__ __forceinline__ float gelu_f(float x) {
    // tanh-approx GELU, branchless 9-op form. t = tanh(u) = 1 - 2/(exp(2u)+1),
    // with 2*log2(e) folded into the polynomial so exp2 is used directly.
    // Overflow-safe: z>>0 -> exp2=inf -> rcp=0 -> t=1; z<<0 -> exp2=0 -> t=-1.
    float z  = x * fmaf(0.10294343f * x, x, 2.3022082f);
    float t  = fmaf(-2.0f, __builtin_amdgcn_rcpf(exp2f(z) + 1.0f), 1.0f);
    float hx = 0.5f * x;
    return fmaf(hx, t, hx);
}

__device__ __forceinline__ bf16x8 ld8(const bf16* p) {       // 16B-aligned
    return *reinterpret_cast<const bf16x8*>(p);
}
__device__ __forceinline__ bf16x8 ld8u(const bf16* p) {      // 8B-aligned (two b64)
    bf16x4v lo = *reinterpret_cast<const bf16x4v*>(p);
    bf16x4v hi = *reinterpret_cast<const bf16x4v*>(p + 4);
    return __builtin_shufflevector(lo, hi, 0, 1, 2, 3, 4, 5, 6, 7);
}
__device__ __forceinline__ f32x4 mfma16(bf16x8 a, bf16x8 b, f32x4 c) {
    return __builtin_amdgcn_mfma_f32_16x16x32_bf16(a, b, c, 0, 0, 0);
}

// ---------------- prep: weight transposes + adjacency softmax ----------------
__global__ void prep_kernel(const float* __restrict__ W1, const float* __restrict__ W2,
                            const float* __restrict__ Wg1, const float* __restrict__ Wg2,
                            const float* __restrict__ adj1, const float* __restrict__ adj2,
                            bf16* __restrict__ w1t, bf16* __restrict__ w2t,
                            bf16* __restrict__ wg1t, bf16* __restrict__ wg2t,
                            float* __restrict__ A1f, float* __restrict__ A2f) {
    int idx = blockIdx.x * 256 + threadIdx.x;
    if (idx < 32768) {                       // W1: r=k(128), c=n(256)
        int r = idx >> 8, c = idx & 255;
        w1t[c * 128 + r] = __float2bfloat16(W1[idx]);
    } else if (idx < 172032) {               // W2: r=k(256), c=n(544)
        int j = idx - 32768;
        int r = j / 544, c = j % 544;
        w2t[c * 256 + r] = __float2bfloat16(W2[j]);
    } else if (idx < 173056) {               // Wg1 -> wg1t[f'][f]
        int j = idx - 172032;
        wg1t[(j & 31) * 32 + (j >> 5)] = __float2bfloat16(Wg1[j]);
    } else if (idx < 174080) {
        int j = idx - 173056;
        wg2t[(j & 31) * 32 + (j >> 5)] = __float2bfloat16(Wg2[j]);
    }
    if (blockIdx.x == 0) {
        int t = threadIdx.x;
        if (t < 17 || (t >= 32 && t < 49)) {
            const float* adj = (t < 17) ? adj1 : adj2;
            float*       A   = (t < 17) ? A1f  : A2f;
            int row = (t < 17) ? t : (t - 32);
            float v[17]; float mx = -1e30f;
            for (int j = 0; j < 17; ++j) { v[j] = adj[row * 17 + j]; mx = fmaxf(mx, v[j]); }
            float s = 0.0f;
            for (int j = 0; j < 17; ++j) { v[j] = __expf(v[j] - mx); s += v[j]; }
            float inv = 1.0f / s;
            for (int j = 0; j < 17; ++j) A[row * 17 + j] = v[j] * inv;
        }
    }
}

// ---------------- prep 2: mixB fragment tables (bf16, B-layout, zero-padded) ----------------
// mb[g][nt][lane][e]: B[k=j][col=i] = A_soft[i][j], i = nt*16+(lane&15), j = (lane>>4)*8+e;
// exact 0 for i>=17 or j>=17. gat_main loads a fragment with one ld8.
__global__ void prep_mixb(const float* __restrict__ A1f, const float* __restrict__ A2f,
                          bf16* __restrict__ mb) {
    int idx = blockIdx.x * 256 + threadIdx.x;      // 2048 entries
    if (idx < 2048) {
        int g = idx >> 10, rem = idx & 1023;
        int nt = rem >> 9, lane = (rem >> 3) & 63, e = rem & 7;
        int i = nt * 16 + (lane & 15);
        int j = (lane >> 4) * 8 + e;
        const float* A = g ? A2f : A1f;
        float v = (i < 17 && j < 17) ? A[i * 17 + j] : 0.0f;
        mb[idx] = __float2bfloat16(v);
    }
}

// ---------------- main fused kernel ----------------
__global__ __launch_bounds__(512, 4)
void gat_main(const float* __restrict__ x,
              const float* __restrict__ b1, const float* __restrict__ b2,
              const float* __restrict__ bg1, const float* __restrict__ bg2,
              const bf16* __restrict__ w1t, const bf16* __restrict__ w2t,
              const bf16* __restrict__ wg1t, const bf16* __restrict__ wg2t,
              const bf16* __restrict__ mb,
              const float* __restrict__ Wc, const float* __restrict__ bc,
              float* __restrict__ out) {
    __shared__ alignas(16) bf16 S[S_ELEMS];
    bf16* xs = S;            // [32][SX]
    bf16* hs = S + 4352;     // [32][SH]

    const int tid  = threadIdx.x;
    const int w    = tid >> 6;      // 0..7
    const int lane = tid & 63;
    const int l    = lane & 15;
    const int q    = lane >> 4;
    const int t0   = blockIdx.x * MT;

    // ---- stage x tile (fp32 -> bf16) ----
    for (int c = tid; c < 1024; c += 512) {
        int row = c >> 5, c4 = c & 31;
        const float4 v = *reinterpret_cast<const float4*>(x + (size_t)(t0 + row) * 128 + c4 * 4);
        bf16 tmp[4] = { __float2bfloat16(v.x), __float2bfloat16(v.y),
                        __float2bfloat16(v.z), __float2bfloat16(v.w) };
        *reinterpret_cast<ushort4*>(xs + row * SX + c4 * 4) =
            *reinterpret_cast<const ushort4*>(tmp);
    }
    __syncthreads();

    // ---- GEMM1: h = gelu(x @ W1 + b1)  [32,128]@[128,256], 2 n-tiles/wave ----
    for (int nt = w * 2; nt < w * 2 + 2; ++nt) {
        int n = nt * 16 + l;
        bf16x8 bfr[4];
        const bf16* wp = w1t + n * 128 + q * 8;
#pragma unroll
        for (int kf = 0; kf < 4; ++kf) bfr[kf] = ld8(wp + kf * 32);
        float bias = b1[n];
#pragma unroll
        for (int mt = 0; mt < 2; ++mt) {
            f32x4 acc = {0.f, 0.f, 0.f, 0.f};
            const bf16* ap = xs + (mt * 16 + l) * SX + q * 8;
#pragma unroll
            for (int kf = 0; kf < 4; ++kf)
                acc = mfma16(ld8(ap + kf * 32), bfr[kf], acc);
            int trow = mt * 16 + q * 4;
#pragma unroll
            for (int r = 0; r < 4; ++r)
                hs[(trow + r) * SH + n] = __float2bfloat16(gelu_f(acc[r] + bias));
        }
    }
    __syncthreads();

    // ---- GEMM2: nodes = h @ W2 + b2 -> NTF[t][f][i] scatter (overlays xs+hs) ----
    {
        bf16x8 af[2][8];    // register-capture all of this thread's hs fragments
#pragma unroll
        for (int mt = 0; mt < 2; ++mt)
#pragma unroll
            for (int kf = 0; kf < 8; ++kf)
                af[mt][kf] = ld8(hs + (mt * 16 + l) * SH + kf * 32 + q * 8);
        __syncthreads();     // hs fully captured before NTF (overlaying) is written

        // zero NTF pad: j=17..19 of every (t,f) row + 16-elem tail (mix over-reads
        // hit these; must be non-NaN; mixB zeros annihilate their contribution)
        for (int z = tid; z < 3072; z += 512) {
            int row = z / 3, k = z - row * 3;
            S[row * SJ + 17 + k] = __float2bfloat16(0.f);
        }
        if (tid < 16) S[NTF_ELEMS + tid] = __float2bfloat16(0.f);

        for (int nt = w; nt < 34; nt += 8) {
            int n = nt * 16 + l;
            float bias = b2[n];
            int i = n >> 5, f = n & 31;
            f32x4 a0 = {0.f, 0.f, 0.f, 0.f}, a1 = {0.f, 0.f, 0.f, 0.f};
            const bf16* wp = w2t + n * 256 + q * 8;
#pragma unroll
            for (int kf = 0; kf < 8; ++kf) {
                bf16x8 bfr = ld8(wp + kf * 32);
                a0 = mfma16(af[0][kf], bfr, a0);
                a1 = mfma16(af[1][kf], bfr, a1);
            }
#pragma unroll
            for (int mt = 0; mt < 2; ++mt) {
                const f32x4 acc = mt ? a1 : a0;
#pragma unroll
                for (int r = 0; r < 4; ++r) {
                    int t = mt * 16 + q * 4 + r;
                    S[t * TFS + f * SJ + i] = __float2bfloat16(acc[r] + bias);
                }
            }
        }
    }
    __syncthreads();
    // ======== from here on, everything is WAVE-LOCAL: no more barriers ========

    bf16* ms_p = S + MS_BASE + w * MSW;    // this wave's [34][36] pair-Ms scratch

    for (int g = 0; g < 2; ++g) {
        const bf16* mbg = mb + g * 1024;
        const bf16* wgt = g ? wg2t : wg1t;
        const float* bg = g ? bg2 : bg1;

        bf16x8 mixB[2] = { ld8(mbg + lane * 8), ld8(mbg + 512 + lane * 8) };
        bf16x8 wfr[2];
#pragma unroll
        for (int nt = 0; nt < 2; ++nt) wfr[nt] = ld8(wgt + (nt * 16 + l) * 32 + q * 8);
        float bgf[2] = { bg[l], bg[16 + l] };

        // two 2-token pairs per wave (wave owns tokens w*4 .. w*4+3)
        for (int p = 0; p < 2; ++p) {
            const int T0 = w * 4 + p * 2;

            // ---- mix GEMM for both tokens of the pair -> pair-Ms (i-major) ----
            // token tl rows: i<16 -> tl*16+i ; i==16 -> 32+tl
#pragma unroll
            for (int u = 0; u < 4; ++u) {              // u = tl*2 + ft
                int tl = u >> 1, ft = u & 1;
                int R = (T0 + tl) * 32 + ft * 16 + l;  // NTF row (t*32+f)
                bf16x8 afr = ld8u(S + R * SJ + q * 8); // pad/overread killed by mixB zeros
                int f0 = ft * 16 + q * 4;              // 4 consecutive f (D-rows)
#pragma unroll
                for (int nt = 0; nt < 2; ++nt) {
                    f32x4 acc = {0.f, 0.f, 0.f, 0.f};
                    acc = mfma16(afr, mixB[nt], acc);
                    union { ushort4 u4; bf16 b[4]; } pk;
#pragma unroll
                    for (int r = 0; r < 4; ++r) pk.b[r] = __float2bfloat16(acc[r]);
                    if (nt == 0) {                     // i = l in 0..15: always valid
                        *reinterpret_cast<ushort4*>(ms_p + (tl * 16 + l) * SMS + f0) = pk.u4;
                    } else if (l == 0) {               // i = 16: row 32+tl
                        *reinterpret_cast<ushort4*>(ms_p + (32 + tl) * SMS + f0) = pk.u4;
                    }
                }
            }

            // ---- Wg GEMM + gelu + residual: 3 m-tiles finish BOTH tokens ----
            // mt 0/1: token T0+mt, dense i-quads 0..15 (unmasked b64 RMW).
            // mt 2:   rows 32/33 = the two i=16 rows; only q==0, r<2 valid.
#pragma unroll
            for (int mt = 0; mt < 3; ++mt) {
                bf16x8 afr = ld8u(ms_p + (mt * 16 + l) * SMS + q * 8);
#pragma unroll
                for (int nt = 0; nt < 2; ++nt) {
                    f32x4 acc = {0.f, 0.f, 0.f, 0.f};
                    acc = mfma16(afr, wfr[nt], acc);
                    int fp = nt * 16 + l;
                    if (mt < 2) {
                        int i0 = q * 4;                // 0,4,8,12 (always < 16)
                        bf16* ptr = S + (T0 + mt) * TFS + fp * SJ + i0;
                        union { ushort4 u4; bf16 b[4]; } old, nw;
                        old.u4 = *reinterpret_cast<const ushort4*>(ptr);
#pragma unroll
                        for (int r = 0; r < 4; ++r) {
                            float v = gelu_f(acc[r] + bgf[nt]) + bf2f(old.b[r]);
                            nw.b[r] = __float2bfloat16(v);
                        }
                        *reinterpret_cast<ushort4*>(ptr) = nw.u4;
                    } else if (q == 0) {
#pragma unroll
                        for (int r = 0; r < 2; ++r) {  // r=0 -> T0 i=16, r=1 -> T0+1 i=16
                            bf16* pp = S + (T0 + r) * TFS + fp * SJ + 16;
                            float v = gelu_f(acc[r] + bgf[nt]) + bf2f(*pp);
                            *pp = __float2bfloat16(v);
                        }
                    }
                }
            }
        }
    }

    // ---- coord projection (wave-local): out = g2 @ Wc + bc (fp32 output) ----
    for (int s = lane; s < 68; s += 64) {
        int tl = s / 17, i = s - tl * 17;
        int t  = w * 4 + tl;
        const bf16* gp = S + t * TFS + i;
        float o0 = bc[0], o1 = bc[1];
#pragma unroll
        for (int f = 0; f < 32; ++f) {
            float v = bf2f(gp[f * SJ]);
            o0 = fmaf(v, Wc[f * 2 + 0], o0);
            o1 = fmaf(v, Wc[f * 2 + 1], o1);
        }
        float2 pr = { o0, o1 };
        reinterpret_cast<float2*>(out)[(size_t)(t0 + t) * 17 + i] = pr;
    }
}

extern "C" void kernel_launch(void* const* d_in, const int* in_sizes, int n_in,
                              void* d_out, int out_size, void* d_ws, size_t ws_size,
                              hipStream_t stream) {
    const float* x    = (const float*)d_in[0];
    const float* W1   = (const float*)d_in[1];
    const float* b1   = (const float*)d_in[2];
    const float* W2   = (const float*)d_in[3];
    const float* b2   = (const float*)d_in[4];
    const float* adj1 = (const float*)d_in[5];
    const float* Wg1  = (const float*)d_in[6];
    const float* bg1  = (const float*)d_in[7];
    const float* adj2 = (const float*)d_in[8];
    const float* Wg2  = (const float*)d_in[9];
    const float* bg2  = (const float*)d_in[10];
    const float* Wc   = (const float*)d_in[11];
    const float* bc   = (const float*)d_in[12];

    char* ws = (char*)d_ws;
    bf16*  w1t  = (bf16*)(ws + 0);        // 65536 B
    bf16*  w2t  = (bf16*)(ws + 65536);    // 278528 B
    bf16*  wg1t = (bf16*)(ws + 344064);   // 2048 B
    bf16*  wg2t = (bf16*)(ws + 346112);   // 2048 B
    float* A1f  = (float*)(ws + 348160);  // 1156 B
    float* A2f  = (float*)(ws + 349376);  // 1156 B
    bf16*  mbt  = (bf16*)(ws + 350592);   // 4096 B (2 layers x 1024 bf16)

    prep_kernel<<<680, 256, 0, stream>>>(W1, W2, Wg1, Wg2, adj1, adj2,
                                         w1t, w2t, wg1t, wg2t, A1f, A2f);
    prep_mixb<<<8, 256, 0, stream>>>(A1f, A2f, mbt);

    const int tokens = 16 * 4096;
    gat_main<<<tokens / MT, 512, 0, stream>>>(x, b1, b2, bg1, bg2,
                                              w1t, w2t, wg1t, wg2t, mbt,
                                              Wc, bc, (float*)d_out);
}